// Round 3
// baseline (121.232 us; speedup 1.0000x reference)
//
#include <hip/hip_runtime.h>
#include <hip/hip_fp16.h>
#include <math.h>

#define NV 10475
#define NDS 2048
#define NHAND 1554
#define NHA 777
#define NCONTACT 300
#define NQ (NHAND + NDS)            // 3602 query rows total

#define GDI_CHUNKS 8
#define GDI_ROWS ((NCONTACT + GDI_CHUNKS - 1) / GDI_CHUNKS)  // 38
#define GDI_GROUPS 41               // col groups of 256: 41*256 = 10496 >= NV
#define GDI_BLOCKS 41               // 41 blocks * 8 waves = 328 = 8*41 items
#define SCAN_BLOCKS 471             // 471*8 = 3768 waves >= 3602 queries
#define THREADS 512

#define GEO_THRESH 0.3f
#define EXT_THRESH 0.02f
#define A1c 0.04f
#define A2c 0.04f
#define B1c 0.07f
#define B2c 0.06f
#define C1c 0.01f
#define C2c 0.01f
#define D1c 0.023f
#define D2c 0.02f
#define CONTACT_W 0.5f
#define INSIDE_W 0.5f
#define HAND_W 1.0f

__device__ __forceinline__ float cand_min(float best, float g, __half2 cxy,
                                          __half cz, float px, float py, float pz) {
    float2 c = __half22float2(cxy);
    float dx = px - c.x;
    float dy = py - c.y;
    float dz = pz - __half2float(cz);
    float d2 = fmaf(dx, dx, fmaf(dy, dy, dz * dz));
    d2 = (g < GEO_THRESH) ? INFINITY : d2;
    return fminf(best, d2);
}

// ---------------------------------------------------------------------------
// Mega kernel. Blocks [0, GDI_BLOCKS): gdi partial-min streaming (contact
// rows, column stripes). Blocks [GDI_BLOCKS, ..): persistent per-wave masked
// nearest-neighbor scan with an atomic query queue.
// ---------------------------------------------------------------------------
__global__ __launch_bounds__(THREADS, 2)
void mega_kernel(const float* __restrict__ verts,
                 const float* __restrict__ geodist,
                 const int* __restrict__ hand_idx,
                 const int* __restrict__ ds,
                 const int* __restrict__ cidx,
                 float* __restrict__ hand_min,
                 float* __restrict__ ds_min,
                 float* __restrict__ pgdi,
                 int* __restrict__ inside,
                 int* __restrict__ counter) {
    const int tid = threadIdx.x;
    const int lane = tid & 63;
    const int wave = tid >> 6;

    if (blockIdx.x < GDI_BLOCKS) {
        // --- gdi role: item = (chunk c, column group g) per wave ---
        const int wv = blockIdx.x * (THREADS / 64) + wave;   // 0..327
        const int c = wv / GDI_GROUPS;                       // 0..7
        const int g = wv % GDI_GROUPS;                       // 0..40
        const int j0 = c * GDI_ROWS;
        const int j1 = (j0 + GDI_ROWS < NCONTACT) ? (j0 + GDI_ROWS) : NCONTACT;
        const int c0 = g * 256 + lane;

        float m0 = INFINITY, m1 = INFINITY, m2 = INFINITY, m3 = INFINITY;
        for (int j = j0; j < j1; ++j) {
            const float* __restrict__ grow = geodist + (size_t)cidx[j] * NV;
            if (c0 < NV)       m0 = fminf(m0, grow[c0]);
            if (c0 + 64 < NV)  m1 = fminf(m1, grow[c0 + 64]);
            if (c0 + 128 < NV) m2 = fminf(m2, grow[c0 + 128]);
            if (c0 + 192 < NV) m3 = fminf(m3, grow[c0 + 192]);
        }
        float* __restrict__ prow = pgdi + (size_t)c * NV;
        if (c0 < NV)       prow[c0] = m0;
        if (c0 + 64 < NV)  prow[c0 + 64] = m1;
        if (c0 + 128 < NV) prow[c0 + 128] = m2;
        if (c0 + 192 < NV) prow[c0 + 192] = m3;
        return;
    }

    // --- scan role ---
    __shared__ __half2 sxy[NV];
    __shared__ __half sz[NV];

    for (int n = tid; n < NV; n += THREADS) {
        sxy[n] = __halves2half2(__float2half(verts[3 * n + 0]),
                                __float2half(verts[3 * n + 1]));
        sz[n] = __float2half(verts[3 * n + 2]);
    }
    __syncthreads();

    for (;;) {
        int it;
        if (lane == 0) it = atomicAdd(counter, 1);
        it = __shfl(it, 0);
        if (it >= NQ) break;

        const bool is_ds = (it >= NHAND);
        const int q = is_ds ? ds[it - NHAND] : hand_idx[it];
        const float* __restrict__ grow = geodist + (size_t)q * NV;

        const float2 pxy = __half22float2(sxy[q]);
        const float px = pxy.x, py = pxy.y;
        const float pz = __half2float(sz[q]);

        const int pre = (4 - ((q * 3) & 3)) & 3;   // (q*NV)%4 == (q*3)%4
        const int nvec = (NV - pre) >> 2;
        const int rem = (NV - pre) & 3;

        float best = INFINITY;

        if (lane < pre) {
            best = cand_min(best, grow[lane], sxy[lane], sz[lane], px, py, pz);
        }
        if (lane < rem) {
            const int n = pre + (nvec << 2) + lane;
            best = cand_min(best, grow[n], sxy[n], sz[n], px, py, pz);
        }

        const float4* __restrict__ grow4 = (const float4*)(grow + pre);
        #pragma unroll 4
        for (int j = lane; j < nvec; j += 64) {
            const float4 g4 = grow4[j];
            const int n = pre + (j << 2);
            best = cand_min(best, g4.x, sxy[n + 0], sz[n + 0], px, py, pz);
            best = cand_min(best, g4.y, sxy[n + 1], sz[n + 1], px, py, pz);
            best = cand_min(best, g4.z, sxy[n + 2], sz[n + 2], px, py, pz);
            best = cand_min(best, g4.w, sxy[n + 3], sz[n + 3], px, py, pz);
        }

        #pragma unroll
        for (int off = 32; off > 0; off >>= 1)
            best = fminf(best, __shfl_down(best, off));

        if (lane == 0) {
            const float d = sqrtf(best + 1e-12f);
            if (is_ds) {
                ds_min[it - NHAND] = d;
                if (!(d > EXT_THRESH)) atomicOr(&inside[q], 1);
            } else {
                hand_min[it] = d;
            }
        }
    }
}

// ---------------------------------------------------------------------------
// Finalize: single block, combines gdi partials + all masked means -> scalar.
// ---------------------------------------------------------------------------
__global__ void finalize_kernel(const float* __restrict__ ds_min,
                                const float* __restrict__ pgdi,
                                const int* __restrict__ ds,
                                const float* __restrict__ hand_min,
                                const float* __restrict__ hw,
                                const int* __restrict__ hand_idx,
                                const int* __restrict__ inside,
                                float* __restrict__ out) {
    float acc[12];
    #pragma unroll
    for (int k = 0; k < 12; ++k) acc[k] = 0.0f;

    const int tid = threadIdx.x;
    const int nthr = blockDim.x;

    for (int i = tid; i < NDS; i += nthr) {
        const float m = ds_min[i];
        const int v = ds[i];
        const bool ins = inside[v] != 0;
        if (!ins) {
            float gdi = pgdi[v];
            #pragma unroll
            for (int c = 1; c < GDI_CHUNKS; ++c)
                gdi = fminf(gdi, pgdi[(size_t)c * NV + v]);
            const float w = 1.0f / (5.0f * gdi + 1.0f);
            acc[0] += A1c * w * tanhf(m / A2c);
            acc[1] += 1.0f;
        } else {
            acc[2] += B1c * tanhf(m / B2c);
            acc[3] += 1.0f;
        }
    }

    for (int h = tid; h < NHAND; h += nthr) {
        const float m = hand_min[h];
        const bool ins = inside[hand_idx[h]] != 0;
        const float w = -0.1f * hw[h] + 1.0f;
        const float o = w * C1c * tanhf(m / C2c);
        const float ii = D1c * tanhf(m / D2c);
        if (h < NHA) {
            if (!ins) { acc[4] += o;  acc[5] += 1.0f; }
            else      { acc[8] += ii; acc[9] += 1.0f; }
        } else {
            if (!ins) { acc[6]  += o;  acc[7]  += 1.0f; }
            else      { acc[10] += ii; acc[11] += 1.0f; }
        }
    }

    __shared__ float red[16][12];
    const int lane = tid & 63;
    const int wave = tid >> 6;
    #pragma unroll
    for (int k = 0; k < 12; ++k) {
        float v = acc[k];
        #pragma unroll
        for (int off = 32; off > 0; off >>= 1)
            v += __shfl_down(v, off);
        acc[k] = v;
    }
    if (lane == 0) {
        #pragma unroll
        for (int k = 0; k < 12; ++k) red[wave][k] = acc[k];
    }
    __syncthreads();
    if (tid == 0) {
        float t[12];
        const int nw = nthr >> 6;
        #pragma unroll
        for (int k = 0; k < 12; ++k) {
            float s = red[0][k];
            for (int w = 1; w < nw; ++w) s += red[w][k];
            t[k] = s;
        }
        const float contactloss = CONTACT_W * (t[0] / fmaxf(t[1], 1.0f));
        const float insideloss  = INSIDE_W  * (t[2] / fmaxf(t[3], 1.0f));
        const float hand_out = t[4] / fmaxf(t[5], 1.0f) + t[6]  / fmaxf(t[7], 1.0f);
        const float hand_in  = t[8] / fmaxf(t[9], 1.0f) + t[10] / fmaxf(t[11], 1.0f);
        out[0] = contactloss + insideloss + HAND_W * (hand_out + hand_in);
    }
}

extern "C" void kernel_launch(void* const* d_in, const int* in_sizes, int n_in,
                              void* d_out, int out_size, void* d_ws, size_t ws_size,
                              hipStream_t stream) {
    const float* vertices = (const float*)d_in[0];  // [1,NV,3]
    const float* geodist  = (const float*)d_in[1];  // [NV,NV]
    const float* hand_w   = (const float*)d_in[2];  // [NHAND]
    const int*   ds       = (const int*)d_in[3];    // [NDS]
    const int*   hand_idx = (const int*)d_in[4];    // [NHAND]
    const int*   cidx     = (const int*)d_in[5];    // [NCONTACT]
    float* out = (float*)d_out;

    // workspace layout (16B-aligned chunks)
    char* p = (char*)d_ws;
    float* hand_min = (float*)p;  p += ((NHAND * 4 + 15) & ~15);
    float* ds_min = (float*)p;    p += ((NDS * 4 + 15) & ~15);
    float* pgdi = (float*)p;      p += ((GDI_CHUNKS * NV * 4 + 15) & ~15);
    int* inside = (int*)p;        p += ((NV * 4 + 15) & ~15);
    int* counter = (int*)p;       p += 16;

    // zero inside[] + queue counter (contiguous region)
    hipMemsetAsync(inside, 0, ((NV * 4 + 15) & ~15) + 16, stream);

    mega_kernel<<<GDI_BLOCKS + SCAN_BLOCKS, THREADS, 0, stream>>>(
        vertices, geodist, hand_idx, ds, cidx,
        hand_min, ds_min, pgdi, inside, counter);

    finalize_kernel<<<1, 1024, 0, stream>>>(ds_min, pgdi, ds, hand_min, hand_w,
                                            hand_idx, inside, out);
}

// Round 4
// 54.650 us; speedup vs baseline: 2.2183x; 2.2183x over previous
//
#include <hip/hip_runtime.h>
#include <hip/hip_fp16.h>
#include <math.h>

#define NV 10475
#define NDS 2048
#define NHAND 1554
#define NHA 777
#define NCONTACT 300
#define NQ (NHAND + NDS)            // 3602 query rows total

#define GDI_CHUNKS 8
#define GDI_ROWS ((NCONTACT + GDI_CHUNKS - 1) / GDI_CHUNKS)  // 38
#define GDI_GROUPS 41               // col groups of 256: 41*256 = 10496 >= NV
#define GDI_BLOCKS 41               // 41 blocks * 8 waves = 328 items
#define SCAN_BLOCKS 471             // 471*8 = 3768 waves >= 3602 queries
#define THREADS 512

#define GEO_THRESH 0.3f
#define EXT_THRESH 0.02f
#define A1c 0.04f
#define A2c 0.04f
#define B1c 0.07f
#define B2c 0.06f
#define C1c 0.01f
#define C2c 0.01f
#define D1c 0.023f
#define D2c 0.02f
#define CONTACT_W 0.5f
#define INSIDE_W 0.5f
#define HAND_W 1.0f

// ---------------------------------------------------------------------------
// Prep: fp16-round vertices -> packed global arrays; zero inside[].
// ---------------------------------------------------------------------------
__global__ void prep_kernel(const float* __restrict__ verts,
                            __half2* __restrict__ gxy,
                            __half* __restrict__ gz,
                            int* __restrict__ inside) {
    const int n = blockIdx.x * 256 + threadIdx.x;
    if (n < NV) {
        gxy[n] = __halves2half2(__float2half(verts[3 * n + 0]),
                                __float2half(verts[3 * n + 1]));
        gz[n] = __float2half(verts[3 * n + 2]);
        inside[n] = 0;
    }
}

__device__ __forceinline__ float cand_min(float best, float g, __half2 cxy,
                                          __half cz, float px, float py, float pz) {
    float2 c = __half22float2(cxy);
    float dx = px - c.x;
    float dy = py - c.y;
    float dz = pz - __half2float(cz);
    float d2 = fmaf(dx, dx, fmaf(dy, dy, dz * dz));
    d2 = (g < GEO_THRESH) ? INFINITY : d2;
    return fminf(best, d2);
}

// ---------------------------------------------------------------------------
// Main kernel. Blocks [0, GDI_BLOCKS): gdi partial-min streaming (contact
// rows, column stripes). Blocks [GDI_BLOCKS, ..): per-wave masked
// nearest-neighbor row scans, STATIC wave->query assignment (no atomics).
// ---------------------------------------------------------------------------
__global__ __launch_bounds__(THREADS, 2)
void main_kernel(const float* __restrict__ geodist,
                 const __half2* __restrict__ gxy,
                 const __half* __restrict__ gz,
                 const int* __restrict__ hand_idx,
                 const int* __restrict__ ds,
                 const int* __restrict__ cidx,
                 float* __restrict__ hand_min,
                 float* __restrict__ ds_min,
                 float* __restrict__ pgdi,
                 int* __restrict__ inside) {
    const int tid = threadIdx.x;
    const int lane = tid & 63;
    const int wave = tid >> 6;

    if (blockIdx.x < GDI_BLOCKS) {
        // --- gdi role: item = (chunk c, column group g) per wave ---
        const int wv = blockIdx.x * (THREADS / 64) + wave;   // 0..327
        const int c = wv / GDI_GROUPS;                       // 0..7
        const int g = wv % GDI_GROUPS;                       // 0..40
        const int j0 = c * GDI_ROWS;
        const int j1 = (j0 + GDI_ROWS < NCONTACT) ? (j0 + GDI_ROWS) : NCONTACT;
        const int c0 = g * 256 + lane;

        float m0 = INFINITY, m1 = INFINITY, m2 = INFINITY, m3 = INFINITY;
        for (int j = j0; j < j1; ++j) {
            const float* __restrict__ grow = geodist + (size_t)cidx[j] * NV;
            if (c0 < NV)       m0 = fminf(m0, grow[c0]);
            if (c0 + 64 < NV)  m1 = fminf(m1, grow[c0 + 64]);
            if (c0 + 128 < NV) m2 = fminf(m2, grow[c0 + 128]);
            if (c0 + 192 < NV) m3 = fminf(m3, grow[c0 + 192]);
        }
        float* __restrict__ prow = pgdi + (size_t)c * NV;
        if (c0 < NV)       prow[c0] = m0;
        if (c0 + 64 < NV)  prow[c0 + 64] = m1;
        if (c0 + 128 < NV) prow[c0 + 128] = m2;
        if (c0 + 192 < NV) prow[c0 + 192] = m3;
        return;
    }

    // --- scan role ---
    __shared__ __align__(16) __half2 sxy[NV];
    __shared__ __align__(16) __half sz[NV];

    {   // vectorized LDS fill from packed global (L2-resident after 1st block)
        float4* dxy4 = (float4*)sxy;
        const float4* sxy4 = (const float4*)gxy;
        for (int i = tid; i < NV / 4; i += THREADS) dxy4[i] = sxy4[i];   // 2618
        float4* dz4 = (float4*)sz;
        const float4* gz4 = (const float4*)gz;
        for (int i = tid; i < NV / 8; i += THREADS) dz4[i] = gz4[i];     // 1309
        // remainders: half2 idx 10472..10474, half idx 10472..10474
        if (tid < 3) {
            sxy[NV - 3 + tid] = gxy[NV - 3 + tid];
            sz[NV - 3 + tid] = gz[NV - 3 + tid];
        }
    }
    __syncthreads();

    const int it = (blockIdx.x - GDI_BLOCKS) * (THREADS / 64) + wave;
    if (it >= NQ) return;

    const bool is_ds = (it >= NHAND);
    const int q = is_ds ? ds[it - NHAND] : hand_idx[it];
    const float* __restrict__ grow = geodist + (size_t)q * NV;

    const float2 pxy = __half22float2(sxy[q]);
    const float px = pxy.x, py = pxy.y;
    const float pz = __half2float(sz[q]);

    const int pre = (4 - ((q * 3) & 3)) & 3;   // (q*NV)%4 == (q*3)%4
    const int nvec = (NV - pre) >> 2;
    const int rem = (NV - pre) & 3;

    float best = INFINITY;

    if (lane < pre) {
        best = cand_min(best, grow[lane], sxy[lane], sz[lane], px, py, pz);
    }
    if (lane < rem) {
        const int n = pre + (nvec << 2) + lane;
        best = cand_min(best, grow[n], sxy[n], sz[n], px, py, pz);
    }

    const float4* __restrict__ grow4 = (const float4*)(grow + pre);
    #pragma unroll 4
    for (int j = lane; j < nvec; j += 64) {
        const float4 g4 = grow4[j];
        const int n = pre + (j << 2);
        best = cand_min(best, g4.x, sxy[n + 0], sz[n + 0], px, py, pz);
        best = cand_min(best, g4.y, sxy[n + 1], sz[n + 1], px, py, pz);
        best = cand_min(best, g4.z, sxy[n + 2], sz[n + 2], px, py, pz);
        best = cand_min(best, g4.w, sxy[n + 3], sz[n + 3], px, py, pz);
    }

    #pragma unroll
    for (int off = 32; off > 0; off >>= 1)
        best = fminf(best, __shfl_down(best, off));

    if (lane == 0) {
        const float d = sqrtf(best + 1e-12f);
        if (is_ds) {
            ds_min[it - NHAND] = d;
            if (!(d > EXT_THRESH)) atomicOr(&inside[q], 1);
        } else {
            hand_min[it] = d;
        }
    }
}

// ---------------------------------------------------------------------------
// Finalize: single block, combines gdi partials + all masked means -> scalar.
// ---------------------------------------------------------------------------
__global__ void finalize_kernel(const float* __restrict__ ds_min,
                                const float* __restrict__ pgdi,
                                const int* __restrict__ ds,
                                const float* __restrict__ hand_min,
                                const float* __restrict__ hw,
                                const int* __restrict__ hand_idx,
                                const int* __restrict__ inside,
                                float* __restrict__ out) {
    float acc[12];
    #pragma unroll
    for (int k = 0; k < 12; ++k) acc[k] = 0.0f;

    const int tid = threadIdx.x;
    const int nthr = blockDim.x;

    for (int i = tid; i < NDS; i += nthr) {
        const float m = ds_min[i];
        const int v = ds[i];
        const bool ins = inside[v] != 0;
        if (!ins) {
            float gdi = pgdi[v];
            #pragma unroll
            for (int c = 1; c < GDI_CHUNKS; ++c)
                gdi = fminf(gdi, pgdi[(size_t)c * NV + v]);
            const float w = 1.0f / (5.0f * gdi + 1.0f);
            acc[0] += A1c * w * tanhf(m / A2c);
            acc[1] += 1.0f;
        } else {
            acc[2] += B1c * tanhf(m / B2c);
            acc[3] += 1.0f;
        }
    }

    for (int h = tid; h < NHAND; h += nthr) {
        const float m = hand_min[h];
        const bool ins = inside[hand_idx[h]] != 0;
        const float w = -0.1f * hw[h] + 1.0f;
        const float o = w * C1c * tanhf(m / C2c);
        const float ii = D1c * tanhf(m / D2c);
        if (h < NHA) {
            if (!ins) { acc[4] += o;  acc[5] += 1.0f; }
            else      { acc[8] += ii; acc[9] += 1.0f; }
        } else {
            if (!ins) { acc[6]  += o;  acc[7]  += 1.0f; }
            else      { acc[10] += ii; acc[11] += 1.0f; }
        }
    }

    __shared__ float red[16][12];
    const int lane = tid & 63;
    const int wave = tid >> 6;
    #pragma unroll
    for (int k = 0; k < 12; ++k) {
        float v = acc[k];
        #pragma unroll
        for (int off = 32; off > 0; off >>= 1)
            v += __shfl_down(v, off);
        acc[k] = v;
    }
    if (lane == 0) {
        #pragma unroll
        for (int k = 0; k < 12; ++k) red[wave][k] = acc[k];
    }
    __syncthreads();
    if (tid == 0) {
        float t[12];
        const int nw = nthr >> 6;
        #pragma unroll
        for (int k = 0; k < 12; ++k) {
            float s = red[0][k];
            for (int w = 1; w < nw; ++w) s += red[w][k];
            t[k] = s;
        }
        const float contactloss = CONTACT_W * (t[0] / fmaxf(t[1], 1.0f));
        const float insideloss  = INSIDE_W  * (t[2] / fmaxf(t[3], 1.0f));
        const float hand_out = t[4] / fmaxf(t[5], 1.0f) + t[6]  / fmaxf(t[7], 1.0f);
        const float hand_in  = t[8] / fmaxf(t[9], 1.0f) + t[10] / fmaxf(t[11], 1.0f);
        out[0] = contactloss + insideloss + HAND_W * (hand_out + hand_in);
    }
}

extern "C" void kernel_launch(void* const* d_in, const int* in_sizes, int n_in,
                              void* d_out, int out_size, void* d_ws, size_t ws_size,
                              hipStream_t stream) {
    const float* vertices = (const float*)d_in[0];  // [1,NV,3]
    const float* geodist  = (const float*)d_in[1];  // [NV,NV]
    const float* hand_w   = (const float*)d_in[2];  // [NHAND]
    const int*   ds       = (const int*)d_in[3];    // [NDS]
    const int*   hand_idx = (const int*)d_in[4];    // [NHAND]
    const int*   cidx     = (const int*)d_in[5];    // [NCONTACT]
    float* out = (float*)d_out;

    // workspace layout (16B-aligned chunks)
    char* p = (char*)d_ws;
    __half2* gxy = (__half2*)p;   p += ((NV * 4 + 15) & ~15);
    __half* gz = (__half*)p;      p += ((NV * 2 + 15) & ~15);
    float* hand_min = (float*)p;  p += ((NHAND * 4 + 15) & ~15);
    float* ds_min = (float*)p;    p += ((NDS * 4 + 15) & ~15);
    float* pgdi = (float*)p;      p += ((GDI_CHUNKS * NV * 4 + 15) & ~15);
    int* inside = (int*)p;        p += ((NV * 4 + 15) & ~15);

    prep_kernel<<<41, 256, 0, stream>>>(vertices, gxy, gz, inside);

    main_kernel<<<GDI_BLOCKS + SCAN_BLOCKS, THREADS, 0, stream>>>(
        geodist, gxy, gz, hand_idx, ds, cidx,
        hand_min, ds_min, pgdi, inside);

    finalize_kernel<<<1, 1024, 0, stream>>>(ds_min, pgdi, ds, hand_min, hand_w,
                                            hand_idx, inside, out);
}

// Round 5
// 46.519 us; speedup vs baseline: 2.6061x; 1.1748x over previous
//
#include <hip/hip_runtime.h>
#include <hip/hip_fp16.h>
#include <math.h>

#define NV 10475
#define NDS 2048
#define NHAND 1554
#define NHA 777
#define NCONTACT 300
#define NQ (NHAND + NDS)             // 3602 query rows
#define NVEC4 (NV / 4)               // 2618 float4 per row
#define TAIL0 (NVEC4 * 4)            // 10472
#define MASK_DW ((NV + 31) / 32)     // 328 dwords of bitmask

#define THREADS 512
#define BLOCKS ((NQ + 7) / 8)        // 451 blocks * 8 waves = 3608 >= NQ

// dynamic LDS layout (bytes)
#define SXY_BYTES ((NV * 4 + 15) & ~15)   // 41904
#define SZ_BYTES  ((NV * 2 + 15) & ~15)   // 20960
#define SMEM_BYTES (SXY_BYTES + SZ_BYTES) // 62864 (< 64 KB)

#define GEO_THRESH 0.3f
#define EXT_THRESH 0.02f
#define A1c 0.04f
#define A2c 0.04f
#define B1c 0.07f
#define B2c 0.06f
#define C1c 0.01f
#define C2c 0.01f
#define D1c 0.023f
#define D2c 0.02f
#define CONTACT_W 0.5f
#define INSIDE_W 0.5f
#define HAND_W 1.0f

__device__ __forceinline__ void upd(float g, float cx, float cy, float cz,
                                    float px, float py, float pz, float& best) {
    float dx = px - cx, dy = py - cy, dz = pz - cz;
    float d2 = fmaf(dx, dx, fmaf(dy, dy, dz * dz));
    best = fminf(best, (g < GEO_THRESH) ? INFINITY : d2);
}

// ---------------------------------------------------------------------------
// Scan kernel: one wave per query row. Each block self-stages fp16-rounded
// vertex coords into LDS (packed half2 xy + half z, vector-readable since the
// global row stream is unaligned-float4 so candidate index n = 4j exactly).
// ds rows also accumulate gdi = min over contact columns via an LDS bitmask.
// ---------------------------------------------------------------------------
__global__ __launch_bounds__(THREADS, 4)
void scan_kernel(const float* __restrict__ verts,
                 const float* __restrict__ geodist,
                 const int* __restrict__ hand_idx,
                 const int* __restrict__ ds,
                 const int* __restrict__ cidx,
                 float* __restrict__ hand_min,
                 float* __restrict__ ds_min,
                 float* __restrict__ gdiq) {
    extern __shared__ __align__(16) char smem[];
    __half2* sxy = (__half2*)smem;                 // [NV]
    __half*  sz  = (__half*)(smem + SXY_BYTES);    // [NV]
    __shared__ unsigned int cmask[MASK_DW];

    const int tid = threadIdx.x;
    const int lane = tid & 63;
    const int wave = tid >> 6;

    // phase 1: zero mask + convert vertices (fp16 round) into LDS
    for (int i = tid; i < MASK_DW; i += THREADS) cmask[i] = 0u;
    for (int n = tid; n < NV; n += THREADS) {
        sxy[n] = __halves2half2(__float2half(verts[3 * n + 0]),
                                __float2half(verts[3 * n + 1]));
        sz[n] = __float2half(verts[3 * n + 2]);
    }
    __syncthreads();
    // phase 2: set contact-column bits
    if (tid < NCONTACT) {
        const int c = cidx[tid];
        atomicOr(&cmask[c >> 5], 1u << (c & 31));
    }
    __syncthreads();

    const int gw = blockIdx.x * (THREADS / 64) + wave;
    if (gw >= NQ) return;

    const bool is_ds = (gw >= NHAND);
    const int i_out = is_ds ? (gw - NHAND) : gw;
    const int q = is_ds ? ds[i_out] : hand_idx[gw];
    const float* __restrict__ grow = geodist + (size_t)q * NV;

    const float2 pxy = __half22float2(sxy[q]);
    const float px = pxy.x, py = pxy.y;
    const float pz = __half2float(sz[q]);

    const float4* __restrict__ g4p = (const float4*)grow;   // 4B-aligned OK on gfx950
    const uint4* __restrict__ sxy4 = (const uint4*)sxy;
    const uint2* __restrict__ sz2 = (const uint2*)sz;

    float best = INFINITY;
    float gb = INFINITY;

    if (is_ds) {
        #pragma unroll 4
        for (int j = lane; j < NVEC4; j += 64) {
            const float4 g4 = g4p[j];
            const uint4 xy = sxy4[j];
            const uint2 zz = sz2[j];
            const unsigned int mb = cmask[j >> 3] >> ((j & 7) * 4);
            const float2 c0 = __half22float2(*(const __half2*)&xy.x);
            const float2 c1 = __half22float2(*(const __half2*)&xy.y);
            const float2 c2 = __half22float2(*(const __half2*)&xy.z);
            const float2 c3 = __half22float2(*(const __half2*)&xy.w);
            const float2 z01 = __half22float2(*(const __half2*)&zz.x);
            const float2 z23 = __half22float2(*(const __half2*)&zz.y);
            upd(g4.x, c0.x, c0.y, z01.x, px, py, pz, best);
            upd(g4.y, c1.x, c1.y, z01.y, px, py, pz, best);
            upd(g4.z, c2.x, c2.y, z23.x, px, py, pz, best);
            upd(g4.w, c3.x, c3.y, z23.y, px, py, pz, best);
            gb = fminf(gb, (mb & 1u) ? g4.x : INFINITY);
            gb = fminf(gb, (mb & 2u) ? g4.y : INFINITY);
            gb = fminf(gb, (mb & 4u) ? g4.z : INFINITY);
            gb = fminf(gb, (mb & 8u) ? g4.w : INFINITY);
        }
    } else {
        #pragma unroll 4
        for (int j = lane; j < NVEC4; j += 64) {
            const float4 g4 = g4p[j];
            const uint4 xy = sxy4[j];
            const uint2 zz = sz2[j];
            const float2 c0 = __half22float2(*(const __half2*)&xy.x);
            const float2 c1 = __half22float2(*(const __half2*)&xy.y);
            const float2 c2 = __half22float2(*(const __half2*)&xy.z);
            const float2 c3 = __half22float2(*(const __half2*)&xy.w);
            const float2 z01 = __half22float2(*(const __half2*)&zz.x);
            const float2 z23 = __half22float2(*(const __half2*)&zz.y);
            upd(g4.x, c0.x, c0.y, z01.x, px, py, pz, best);
            upd(g4.y, c1.x, c1.y, z01.y, px, py, pz, best);
            upd(g4.z, c2.x, c2.y, z23.x, px, py, pz, best);
            upd(g4.w, c3.x, c3.y, z23.y, px, py, pz, best);
        }
    }

    if (lane < NV - TAIL0) {   // 3 tail candidates
        const int n = TAIL0 + lane;
        const float g = grow[n];
        const float2 c = __half22float2(sxy[n]);
        const float zc = __half2float(sz[n]);
        upd(g, c.x, c.y, zc, px, py, pz, best);
        if (is_ds) {
            const unsigned int bit = (cmask[n >> 5] >> (n & 31)) & 1u;
            gb = fminf(gb, bit ? g : INFINITY);
        }
    }

    #pragma unroll
    for (int off = 32; off > 0; off >>= 1) {
        best = fminf(best, __shfl_down(best, off));
        gb = fminf(gb, __shfl_down(gb, off));
    }

    if (lane == 0) {
        const float d = sqrtf(best + 1e-12f);
        if (is_ds) {
            ds_min[i_out] = d;
            gdiq[i_out] = gb;
        } else {
            hand_min[gw] = d;
        }
    }
}

// ---------------------------------------------------------------------------
// Finalize: single block. Builds the inside-vertex bitmask in LDS (exactly
// the reference's scatter-max over ds, duplicate-safe), then all masked means.
// ---------------------------------------------------------------------------
__global__ void finalize_kernel(const float* __restrict__ ds_min,
                                const float* __restrict__ gdiq,
                                const int* __restrict__ ds,
                                const float* __restrict__ hand_min,
                                const float* __restrict__ hw,
                                const int* __restrict__ hand_idx,
                                float* __restrict__ out) {
    __shared__ unsigned int imask[MASK_DW];
    const int tid = threadIdx.x;
    const int nthr = blockDim.x;

    for (int i = tid; i < MASK_DW; i += nthr) imask[i] = 0u;
    __syncthreads();
    for (int i = tid; i < NDS; i += nthr) {
        if (!(ds_min[i] > EXT_THRESH)) {
            const int v = ds[i];
            atomicOr(&imask[v >> 5], 1u << (v & 31));
        }
    }
    __syncthreads();

    float acc[12];
    #pragma unroll
    for (int k = 0; k < 12; ++k) acc[k] = 0.0f;

    for (int i = tid; i < NDS; i += nthr) {
        const float m = ds_min[i];
        const int v = ds[i];
        const bool ins = (imask[v >> 5] >> (v & 31)) & 1u;
        if (!ins) {
            const float w = 1.0f / (5.0f * gdiq[i] + 1.0f);
            acc[0] += A1c * w * tanhf(m / A2c);
            acc[1] += 1.0f;
        } else {
            acc[2] += B1c * tanhf(m / B2c);
            acc[3] += 1.0f;
        }
    }

    for (int h = tid; h < NHAND; h += nthr) {
        const float m = hand_min[h];
        const int v = hand_idx[h];
        const bool ins = (imask[v >> 5] >> (v & 31)) & 1u;
        const float w = -0.1f * hw[h] + 1.0f;
        const float o = w * C1c * tanhf(m / C2c);
        const float ii = D1c * tanhf(m / D2c);
        if (h < NHA) {
            if (!ins) { acc[4] += o;  acc[5] += 1.0f; }
            else      { acc[8] += ii; acc[9] += 1.0f; }
        } else {
            if (!ins) { acc[6]  += o;  acc[7]  += 1.0f; }
            else      { acc[10] += ii; acc[11] += 1.0f; }
        }
    }

    __shared__ float red[16][12];
    const int lane = tid & 63;
    const int wave = tid >> 6;
    #pragma unroll
    for (int k = 0; k < 12; ++k) {
        float v = acc[k];
        #pragma unroll
        for (int off = 32; off > 0; off >>= 1)
            v += __shfl_down(v, off);
        acc[k] = v;
    }
    if (lane == 0) {
        #pragma unroll
        for (int k = 0; k < 12; ++k) red[wave][k] = acc[k];
    }
    __syncthreads();
    if (tid == 0) {
        float t[12];
        const int nw = nthr >> 6;
        #pragma unroll
        for (int k = 0; k < 12; ++k) {
            float s = red[0][k];
            for (int w = 1; w < nw; ++w) s += red[w][k];
            t[k] = s;
        }
        const float contactloss = CONTACT_W * (t[0] / fmaxf(t[1], 1.0f));
        const float insideloss  = INSIDE_W  * (t[2] / fmaxf(t[3], 1.0f));
        const float hand_out = t[4] / fmaxf(t[5], 1.0f) + t[6]  / fmaxf(t[7], 1.0f);
        const float hand_in  = t[8] / fmaxf(t[9], 1.0f) + t[10] / fmaxf(t[11], 1.0f);
        out[0] = contactloss + insideloss + HAND_W * (hand_out + hand_in);
    }
}

extern "C" void kernel_launch(void* const* d_in, const int* in_sizes, int n_in,
                              void* d_out, int out_size, void* d_ws, size_t ws_size,
                              hipStream_t stream) {
    const float* vertices = (const float*)d_in[0];  // [1,NV,3]
    const float* geodist  = (const float*)d_in[1];  // [NV,NV]
    const float* hand_w   = (const float*)d_in[2];  // [NHAND]
    const int*   ds       = (const int*)d_in[3];    // [NDS]
    const int*   hand_idx = (const int*)d_in[4];    // [NHAND]
    const int*   cidx     = (const int*)d_in[5];    // [NCONTACT]
    float* out = (float*)d_out;

    char* p = (char*)d_ws;
    float* hand_min = (float*)p;  p += ((NHAND * 4 + 15) & ~15);
    float* ds_min = (float*)p;    p += ((NDS * 4 + 15) & ~15);
    float* gdiq = (float*)p;      p += ((NDS * 4 + 15) & ~15);

    scan_kernel<<<BLOCKS, THREADS, SMEM_BYTES, stream>>>(
        vertices, geodist, hand_idx, ds, cidx, hand_min, ds_min, gdiq);

    finalize_kernel<<<1, 1024, 0, stream>>>(ds_min, gdiq, ds, hand_min,
                                            hand_w, hand_idx, out);
}